// Round 12
// baseline (53.654 us; speedup 1.0000x reference)
//
#include <hip/hip_runtime.h>

// Problem constants
#define B_IMG 8
#define C_IN  16
#define COUT  64
#define H0    36
#define H1    6
#define NB    6
// OH=OW=16; output [8][64][16][16]

typedef float f32x2 __attribute__((ext_vector_type(2)));

__device__ __forceinline__ float sigf(float v) { return 1.0f / (1.0f + __expf(-v)); }

// 6-bit multilinear interp, delta-form table in registers.
// g[0] contracts the MSB ... g[5] the LSB (matches reference einsum order).
__device__ __forceinline__ float lut_contract_reg(const float4 lo4[8], const float4 dd4[8],
                                                  const float g[NB]) {
    f32x2 v[16];
    const float g0 = g[0];
#pragma unroll
    for (int q = 0; q < 8; ++q) {
        v[2*q+0] = (f32x2){lo4[q].x, lo4[q].y} + (f32x2){dd4[q].x, dd4[q].y} * g0;
        v[2*q+1] = (f32x2){lo4[q].z, lo4[q].w} + (f32x2){dd4[q].z, dd4[q].w} * g0;
    }
#pragma unroll
    for (int i = 1; i < 5; ++i) {
        const int vh = 16 >> i;
        const float gi = g[i];
#pragma unroll
        for (int r = 0; r < vh; ++r)
            v[r] += (v[r + vh] - v[r]) * gi;
    }
    return v[0].x + (v[0].y - v[0].x) * g[5];
}

// Load a raw 64-entry table straight from global (wave-uniform address ->
// L1-broadcast float4 loads), sigmoid inline, build delta form in VGPRs.
// No LDS involvement at all.
__device__ __forceinline__ void load_sig_tbl(const float* __restrict__ tb,
                                             float4 lo4[8], float4 dd4[8]) {
    const float4* tp = (const float4*)tb;
#pragma unroll
    for (int q = 0; q < 8; ++q) {
        const float4 a = tp[q], b = tp[q + 8];
        float4 l, d;
        l.x = sigf(a.x); l.y = sigf(a.y); l.z = sigf(a.z); l.w = sigf(a.w);
        d.x = sigf(b.x) - l.x; d.y = sigf(b.y) - l.y;
        d.z = sigf(b.z) - l.z; d.w = sigf(b.w) - l.w;
        lo4[q] = l; dd4[q] = d;
    }
}

// Single fused kernel: block = (channel t, image img), 512 threads = 8 waves,
// 256 pixels. Tables: global -> VGPR (sigmoid inline), NEVER through LDS.
// LDS holds only h0/h1 activations + decoded gather metadata (~45 KB).
__global__ __launch_bounds__(512) void lutone_kernel(
    const float* __restrict__ x,
    const int*   __restrict__ idx0,
    const float* __restrict__ t0,
    const int*   __restrict__ idx1,
    const float* __restrict__ t1,
    const int*   __restrict__ idx2,
    const float* __restrict__ t2,
    float*       __restrict__ out)
{
    __shared__ float h0s[H0*256];      // [raw node][px] — bank = px, conflict-free
    __shared__ float h1s[H1*256];
    __shared__ int   metaL[H0*NB*2];   // per (node,i): {off, rem}
    __shared__ int   idx1L[H1*NB];
    __shared__ int   idx2L[NB];

    const int tid  = threadIdx.x;
    const int w    = tid >> 6;
    const int lane = tid & 63;
    const int t    = blockIdx.x & 63;
    const int img  = blockIdx.x >> 6;

    // ---- decode idx0 -> LDS meta (one thread per (node,bit)) ----
    if (tid < H0*NB) {
        const int raw = idx0[(size_t)t*(H0*NB) + tid];
        const int c2  = raw / 25;
        const int rem = raw - 25*c2;                   // kh*5 + kw
        const int kh  = rem / 5, kw = rem - 5*kh;
        metaL[tid*2 + 0] = c2*1024 + kh*32 + kw - 66;  // -(2*32+2) halo shift
        metaL[tid*2 + 1] = rem;
    }
    if (tid < H1*NB) idx1L[tid] = idx1[(size_t)t*(H1*NB) + tid];
    if (tid < NB)    idx2L[tid] = idx2[(size_t)t*NB + tid];

    // ---- wave-uniform used-node mask (scalar pipe) ----
    const int* i1base = idx1 + t*(H1*NB);
    unsigned long long umask = 0ull;
#pragma unroll
    for (int j = 0; j < H1*NB; ++j) umask |= 1ull << i1base[j];

    // ---- per-lane pixel geometry: base addr + 25-bit (kh,kw) validity mask ----
    int base[4], vmask[4];
#pragma unroll
    for (int c = 0; c < 4; ++c) {
        const int p  = (c << 6) + lane;
        const int oh = p >> 4, ow = p & 15;
        base[c] = img*16384 + oh*64 + ow*2;            // oh2*32 + ow2
        const int hm = 0x1F ^ ((oh == 0) ? 0x03 : 0) ^ ((oh == 15) ? 0x10 : 0);
        const int wm = 0x1F ^ ((ow == 0) ? 0x03 : 0) ^ ((ow == 15) ? 0x10 : 0);
        int vm = 0;
#pragma unroll
        for (int kh = 0; kh < 5; ++kh)
            vm |= ((hm >> kh) & 1) ? (wm << (5*kh)) : 0;
        vmask[c] = vm;
    }

    // ---- this wave's node assignment (<=5 nodes, named regs: rule #20) ----
    int myn0 = -1, myn1 = -1, myn2 = -1, myn3 = -1, myn4 = -1;
    {
        int cnt = 0;
        for (int n = 0; n < H0; ++n) {
            if (!((umask >> n) & 1ull)) continue;
            const int slot = cnt++;
            if ((slot & 7) != w) continue;
            const int k = slot >> 3;
            if      (k == 0) myn0 = n;
            else if (k == 1) myn1 = n;
            else if (k == 2) myn2 = n;
            else if (k == 3) myn3 = n;
            else             myn4 = n;
        }
    }
    __syncthreads();   // metaL ready

    // ---- phase A: layer 0; table global->VGPR per node, 4 chunk-contractions ----
#define NODE_A(NN)                                                           \
    if ((NN) >= 0) {                                                         \
        const int4* mp = (const int4*)(metaL + (NN)*12);                     \
        const int4 ma = mp[0], mb = mp[1], mc = mp[2];                       \
        const int off_[NB] = {ma.x, ma.z, mb.x, mb.z, mc.x, mc.z};           \
        const int rem_[NB] = {ma.y, ma.w, mb.y, mb.w, mc.y, mc.w};           \
        float4 lo4[8], dd4[8];                                               \
        load_sig_tbl(t0 + ((size_t)t*H0 + (NN))*64, lo4, dd4);               \
        _Pragma("unroll")                                                    \
        for (int c = 0; c < 4; ++c) {                                        \
            float g[NB];                                                     \
            _Pragma("unroll")                                                \
            for (int i = 0; i < NB; ++i) {                                   \
                const bool ok = ((vmask[c] >> rem_[i]) & 1) != 0;            \
                const float v = x[ok ? (base[c] + off_[i]) : 0];             \
                g[i] = ok ? v : 0.0f;                                        \
            }                                                                \
            h0s[(NN)*256 + (c << 6) + lane] = lut_contract_reg(lo4, dd4, g); \
        }                                                                    \
    }
    NODE_A(myn0)
    NODE_A(myn1)
    NODE_A(myn2)
    NODE_A(myn3)
    NODE_A(myn4)
#undef NODE_A
    __syncthreads();

    // ---- phase B: layer 1; waves 0..5 own one node (table in VGPRs), 4 chunks ----
    if (w < H1) {
        float4 lo4[8], dd4[8];
        load_sig_tbl(t1 + ((size_t)t*H1 + w)*64, lo4, dd4);
        const int* i1 = idx1L + w*NB;
        const int s0 = i1[0], s1 = i1[1], s2 = i1[2];
        const int s3 = i1[3], s4 = i1[4], s5 = i1[5];
#pragma unroll
        for (int c = 0; c < 4; ++c) {
            const int px = (c << 6) + lane;
            float g[NB];
            g[0] = h0s[s0*256 + px]; g[1] = h0s[s1*256 + px]; g[2] = h0s[s2*256 + px];
            g[3] = h0s[s3*256 + px]; g[4] = h0s[s4*256 + px]; g[5] = h0s[s5*256 + px];
            h1s[w*256 + px] = lut_contract_reg(lo4, dd4, g);
        }
    }
    __syncthreads();

    // ---- phase C: layer 2; waves 0..3 take one 64-px chunk each ----
    if (w < 4) {
        float4 lo4[8], dd4[8];
        load_sig_tbl(t2 + (size_t)t*64, lo4, dd4);
        const int px = (w << 6) + lane;
        float g[NB];
#pragma unroll
        for (int i = 0; i < NB; ++i) g[i] = h1s[idx2L[i]*256 + px];
        out[((size_t)img*COUT + t)*256 + px] = lut_contract_reg(lo4, dd4, g);
    }
}

extern "C" void kernel_launch(void* const* d_in, const int* in_sizes, int n_in,
                              void* d_out, int out_size, void* d_ws, size_t ws_size,
                              hipStream_t stream) {
    const float* x      = (const float*)d_in[0];
    const int*   idx0   = (const int*)  d_in[1];
    const float* table0 = (const float*)d_in[2];
    const int*   idx1   = (const int*)  d_in[3];
    const float* table1 = (const float*)d_in[4];
    const int*   idx2   = (const int*)  d_in[5];
    const float* table2 = (const float*)d_in[6];
    float* out = (float*)d_out;

    lutone_kernel<<<COUT * B_IMG, 512, 0, stream>>>(
        x, idx0, table0, idx1, table1, idx2, table2, out);
}

// Round 13
// 22.642 us; speedup vs baseline: 2.3697x; 2.3697x over previous
//
#include <hip/hip_runtime.h>

// Problem constants
#define B_IMG 8
#define C_IN  16
#define COUT  64
#define H0    36
#define H1    6
#define NB    6
#define NNODE 43
// OH=OW=16; output [8][64][16][16]

typedef float f32x2 __attribute__((ext_vector_type(2)));

__device__ __forceinline__ float sigf(float v) { return 1.0f / (1.0f + __expf(-v)); }
__device__ __forceinline__ float4 sig4(float4 a) {
    return make_float4(sigf(a.x), sigf(a.y), sigf(a.z), sigf(a.w));
}

// Pair-chunk 6-bit multilinear interp from an LDS delta table.
// Each table float4 is read ONCE and immediately consumed by level-0 of BOTH
// accumulators — the compiler cannot shrink the table's live range by
// re-reading it per chunk (the R3/R12 VGPR=32/64 pathology).
// g[0] contracts the MSB ... g[5] the LSB (matches reference einsum order).
__device__ __forceinline__ void lut_contract_pair(
    const float* tb, const float gA[NB], const float gB[NB],
    float* outA, float* outB)
{
    f32x2 vA[16], vB[16];
    const float4* t4 = (const float4*)tb;
    const float a0 = gA[0], b0 = gB[0];
#pragma unroll
    for (int q = 0; q < 8; ++q) {
        const float4 lo = t4[q];
        const float4 dd = t4[q + 8];
        const f32x2 lo01 = {lo.x, lo.y}, lo23 = {lo.z, lo.w};
        const f32x2 dd01 = {dd.x, dd.y}, dd23 = {dd.z, dd.w};
        vA[2*q]   = lo01 + dd01 * a0;
        vA[2*q+1] = lo23 + dd23 * a0;
        vB[2*q]   = lo01 + dd01 * b0;
        vB[2*q+1] = lo23 + dd23 * b0;
    }
#pragma unroll
    for (int i = 1; i < 5; ++i) {
        const int vh = 16 >> i;
        const float ai = gA[i], bi = gB[i];
#pragma unroll
        for (int r = 0; r < vh; ++r) {
            vA[r] += (vA[r + vh] - vA[r]) * ai;
            vB[r] += (vB[r + vh] - vB[r]) * bi;
        }
    }
    *outA = vA[0].x + (vA[0].y - vA[0].x) * gA[5];
    *outB = vB[0].x + (vB[0].y - vB[0].x) * gB[5];
}

// Single fused kernel: block = (channel t, image img), 512 threads = 8 waves,
// 256 pixels (4 chunks of 64, processed as 2 pairs).
__global__ __launch_bounds__(512) void lutone_kernel(
    const float* __restrict__ x,
    const int*   __restrict__ idx0,
    const float* __restrict__ t0,
    const int*   __restrict__ idx1,
    const float* __restrict__ t1,
    const int*   __restrict__ idx2,
    const float* __restrict__ t2,
    float*       __restrict__ out)
{
    __shared__ float tblL[NNODE*64];   // sigmoid'd delta tables: lo[32]|dd[32]
    __shared__ float h0s[H0*256];      // [raw node][px] — bank = px%32, 2-way free
    __shared__ float h1s[H1*256];
    __shared__ int   metaL[H0*NB*2];   // per (node,i): {off, rem}
    __shared__ int   idx1L[H1*NB];
    __shared__ int   idx2L[NB];

    const int tid  = threadIdx.x;
    const int w    = tid >> 6;
    const int lane = tid & 63;
    const int t    = blockIdx.x & 63;
    const int img  = blockIdx.x >> 6;

    // ---- stage sigmoid'd delta tables into LDS (float4-vectorized, 1 round) ----
    {
        float4* tbl4 = (float4*)tblL;
        for (int e = tid; e < NNODE*8; e += 512) {
            const int node = e >> 3, q = e & 7;
            const float* src = (node < H0)      ? t0 + ((size_t)t*H0 + node)*64
                             : (node < H0+H1)   ? t1 + ((size_t)t*H1 + node - H0)*64
                                                : t2 + (size_t)t*64;
            const float4* s4 = (const float4*)src;
            const float4 lo = sig4(s4[q]);
            const float4 hi = sig4(s4[q + 8]);
            tbl4[node*16 + q]     = lo;
            tbl4[node*16 + 8 + q] = make_float4(hi.x - lo.x, hi.y - lo.y,
                                                hi.z - lo.z, hi.w - lo.w);
        }
    }
    // ---- decode idx0 -> LDS meta (one thread per (node,bit)) ----
    if (tid < H0*NB) {
        const int raw = idx0[(size_t)t*(H0*NB) + tid];
        const int c2  = raw / 25;
        const int rem = raw - 25*c2;                   // kh*5 + kw
        const int kh  = rem / 5, kw = rem - 5*kh;
        metaL[tid*2 + 0] = c2*1024 + kh*32 + kw - 66;  // -(2*32+2) halo shift
        metaL[tid*2 + 1] = rem;
    }
    if (tid < H1*NB) idx1L[tid] = idx1[(size_t)t*(H1*NB) + tid];
    if (tid < NB)    idx2L[tid] = idx2[(size_t)t*NB + tid];

    // ---- wave-uniform used-node mask (scalar pipe) ----
    const int* i1base = idx1 + t*(H1*NB);
    unsigned long long umask = 0ull;
#pragma unroll
    for (int j = 0; j < H1*NB; ++j) umask |= 1ull << i1base[j];

    // ---- per-lane pixel geometry: base addr + 25-bit (kh,kw) validity mask ----
    int base[4], vmask[4];
#pragma unroll
    for (int c = 0; c < 4; ++c) {
        const int p  = (c << 6) + lane;
        const int oh = p >> 4, ow = p & 15;
        base[c] = img*16384 + oh*64 + ow*2;            // oh2*32 + ow2
        const int hm = 0x1F ^ ((oh == 0) ? 0x03 : 0) ^ ((oh == 15) ? 0x10 : 0);
        const int wm = 0x1F ^ ((ow == 0) ? 0x03 : 0) ^ ((ow == 15) ? 0x10 : 0);
        int vm = 0;
#pragma unroll
        for (int kh = 0; kh < 5; ++kh)
            vm |= ((hm >> kh) & 1) ? (wm << (5*kh)) : 0;
        vmask[c] = vm;
    }

    // ---- this wave's node assignment (<=5 nodes, named regs: rule #20) ----
    int myn0 = -1, myn1 = -1, myn2 = -1, myn3 = -1, myn4 = -1;
    {
        int cnt = 0;
        for (int n = 0; n < H0; ++n) {
            if (!((umask >> n) & 1ull)) continue;
            const int slot = cnt++;
            if ((slot & 7) != w) continue;
            const int k = slot >> 3;
            if      (k == 0) myn0 = n;
            else if (k == 1) myn1 = n;
            else if (k == 2) myn2 = n;
            else if (k == 3) myn3 = n;
            else             myn4 = n;
        }
    }
    __syncthreads();   // tblL + metaL ready

    // ---- phase A: layer 0; per node: 2 pair-contractions (table read 2x) ----
#define GATH(dst, C)                                                         \
    _Pragma("unroll")                                                        \
    for (int i = 0; i < NB; ++i) {                                           \
        const bool ok = ((vmask[C] >> rem_[i]) & 1) != 0;                    \
        const float v = x[ok ? (base[C] + off_[i]) : 0];                     \
        dst[i] = ok ? v : 0.0f;                                              \
    }
#define NODE_A(NN)                                                           \
    if ((NN) >= 0) {                                                         \
        const int4* mp = (const int4*)(metaL + (NN)*12);                     \
        const int4 ma = mp[0], mb = mp[1], mc = mp[2];                       \
        const int off_[NB] = {ma.x, ma.z, mb.x, mb.z, mc.x, mc.z};           \
        const int rem_[NB] = {ma.y, ma.w, mb.y, mb.w, mc.y, mc.w};           \
        float g0_[NB], g1_[NB], g2_[NB], g3_[NB];                            \
        GATH(g0_, 0) GATH(g1_, 1) GATH(g2_, 2) GATH(g3_, 3)                  \
        float rA, rB;                                                        \
        lut_contract_pair(tblL + (NN)*64, g0_, g1_, &rA, &rB);               \
        h0s[(NN)*256 +   0 + lane] = rA;                                     \
        h0s[(NN)*256 +  64 + lane] = rB;                                     \
        lut_contract_pair(tblL + (NN)*64, g2_, g3_, &rA, &rB);               \
        h0s[(NN)*256 + 128 + lane] = rA;                                     \
        h0s[(NN)*256 + 192 + lane] = rB;                                     \
    }
    NODE_A(myn0)
    NODE_A(myn1)
    NODE_A(myn2)
    NODE_A(myn3)
    NODE_A(myn4)
#undef NODE_A
#undef GATH
    __syncthreads();

    // ---- phase B: layer 1; waves 0..5 own one node, 2 pair-contractions ----
    if (w < H1) {
        const int* i1 = idx1L + w*NB;
        const int s0 = i1[0], s1 = i1[1], s2 = i1[2];
        const int s3 = i1[3], s4 = i1[4], s5 = i1[5];
        const float* tb = tblL + (H0 + w)*64;
#pragma unroll
        for (int p = 0; p < 2; ++p) {
            const int pxA = (p*2    ) * 64 + lane;
            const int pxB = (p*2 + 1) * 64 + lane;
            float gA[NB], gB[NB];
            gA[0] = h0s[s0*256 + pxA]; gB[0] = h0s[s0*256 + pxB];
            gA[1] = h0s[s1*256 + pxA]; gB[1] = h0s[s1*256 + pxB];
            gA[2] = h0s[s2*256 + pxA]; gB[2] = h0s[s2*256 + pxB];
            gA[3] = h0s[s3*256 + pxA]; gB[3] = h0s[s3*256 + pxB];
            gA[4] = h0s[s4*256 + pxA]; gB[4] = h0s[s4*256 + pxB];
            gA[5] = h0s[s5*256 + pxA]; gB[5] = h0s[s5*256 + pxB];
            float rA, rB;
            lut_contract_pair(tb, gA, gB, &rA, &rB);
            h1s[w*256 + pxA] = rA;
            h1s[w*256 + pxB] = rB;
        }
    }
    __syncthreads();

    // ---- phase C: layer 2; waves 0,1 take one pair each ----
    if (w < 2) {
        const int s0 = idx2L[0], s1 = idx2L[1], s2 = idx2L[2];
        const int s3 = idx2L[3], s4 = idx2L[4], s5 = idx2L[5];
        const int pxA = (w*2    ) * 64 + lane;
        const int pxB = (w*2 + 1) * 64 + lane;
        float gA[NB], gB[NB];
        gA[0] = h1s[s0*256 + pxA]; gB[0] = h1s[s0*256 + pxB];
        gA[1] = h1s[s1*256 + pxA]; gB[1] = h1s[s1*256 + pxB];
        gA[2] = h1s[s2*256 + pxA]; gB[2] = h1s[s2*256 + pxB];
        gA[3] = h1s[s3*256 + pxA]; gB[3] = h1s[s3*256 + pxB];
        gA[4] = h1s[s4*256 + pxA]; gB[4] = h1s[s4*256 + pxB];
        gA[5] = h1s[s5*256 + pxA]; gB[5] = h1s[s5*256 + pxB];
        float rA, rB;
        lut_contract_pair(tblL + (H0 + H1)*64, gA, gB, &rA, &rB);
        float* op = out + ((size_t)img*COUT + t)*256;
        op[pxA] = rA;
        op[pxB] = rB;
    }
}

extern "C" void kernel_launch(void* const* d_in, const int* in_sizes, int n_in,
                              void* d_out, int out_size, void* d_ws, size_t ws_size,
                              hipStream_t stream) {
    const float* x      = (const float*)d_in[0];
    const int*   idx0   = (const int*)  d_in[1];
    const float* table0 = (const float*)d_in[2];
    const int*   idx1   = (const int*)  d_in[3];
    const float* table1 = (const float*)d_in[4];
    const int*   idx2   = (const int*)  d_in[5];
    const float* table2 = (const float*)d_in[6];
    float* out = (float*)d_out;

    lutone_kernel<<<COUT * B_IMG, 512, 0, stream>>>(
        x, idx0, table0, idx1, table1, idx2, table2, out);
}